// Round 4
// baseline (185.722 us; speedup 1.0000x reference)
//
#include <hip/hip_runtime.h>

// Rank2SymmetricTensorHead — wave-per-node, DPP-reduced, algebra-factored.
// layernorm is affine per edge => per-node S1[6][9],S2[6],S3[6] suffice;
// per-edge mu/var from per-node mbar[9] + Gram[45].
// One wave owns one node end-to-end: no __syncthreads, reductions on the
// VALU pipe (DPP row_shr/row_bcast), minimal DS-pipe traffic.

#define SQ3  1.73205080756887729f
#define SQ15 3.87298334620741688f
#define SQ5  2.23606797749978970f

__device__ __forceinline__ float dpp_sum64(float v) {
    // 64-lane sum; total lands in lane 63. All VALU, no DS pipe.
    int x;
    x = __builtin_amdgcn_update_dpp(0, __float_as_int(v), 0x111, 0xF, 0xF, true); v += __int_as_float(x);
    x = __builtin_amdgcn_update_dpp(0, __float_as_int(v), 0x112, 0xF, 0xF, true); v += __int_as_float(x);
    x = __builtin_amdgcn_update_dpp(0, __float_as_int(v), 0x114, 0xF, 0xF, true); v += __int_as_float(x);
    x = __builtin_amdgcn_update_dpp(0, __float_as_int(v), 0x118, 0xF, 0xF, true); v += __int_as_float(x);
    x = __builtin_amdgcn_update_dpp(0, __float_as_int(v), 0x142, 0xA, 0xF, true); v += __int_as_float(x);
    x = __builtin_amdgcn_update_dpp(0, __float_as_int(v), 0x143, 0xC, 0xF, true); v += __int_as_float(x);
    return v;
}

__device__ __forceinline__ void wave_fence() {
    __builtin_amdgcn_wave_barrier();
    asm volatile("" ::: "memory");
}

__global__ void preproc_kernel(const int* __restrict__ idx1, const int* __restrict__ batch,
                               int* __restrict__ cnt, int* __restrict__ bcnt,
                               int* __restrict__ elist, int slot, int E, int N) {
    const int i = blockIdx.x * blockDim.x + threadIdx.x;
    const int i4 = i * 4;
    if (i4 + 3 < E) {
        const int4 v = *(const int4*)&idx1[i4];
        int p;
        p = atomicAdd(&cnt[v.x], 1); if (p < slot) elist[(size_t)v.x * slot + p] = i4;
        p = atomicAdd(&cnt[v.y], 1); if (p < slot) elist[(size_t)v.y * slot + p] = i4 + 1;
        p = atomicAdd(&cnt[v.z], 1); if (p < slot) elist[(size_t)v.z * slot + p] = i4 + 2;
        p = atomicAdd(&cnt[v.w], 1); if (p < slot) elist[(size_t)v.w * slot + p] = i4 + 3;
    } else {
        for (int k = i4; k < E; ++k) {
            const int nn = idx1[k];
            const int p = atomicAdd(&cnt[nn], 1);
            if (p < slot) elist[(size_t)nn * slot + p] = k;
        }
    }
    if (i < N) atomicAdd(&bcnt[batch[i]], 1);
}

__global__ __launch_bounds__(256)
void node_kernel(const float* __restrict__ emb, const float* __restrict__ vec,
                 const int* __restrict__ cnt, const int* __restrict__ elist, int slot,
                 const float* __restrict__ sph_w, const float* __restrict__ ln_w,
                 const float* __restrict__ ln_b,
                 const float* __restrict__ W1, const float* __restrict__ b1,
                 const float* __restrict__ W2, const float* __restrict__ b2,
                 const int* __restrict__ batch, float* __restrict__ r2s, int N)
{
    const int lane = threadIdx.x & 63;
    const int wv   = threadIdx.x >> 6;
    const int n    = blockIdx.x * 4 + wv;
    if (n >= N) return;

    __shared__ float escr[4][64][20];   // per-edge scratch: t1[9],mru,op[6],one
    __shared__ float statsL[4][56];     // mbar[9] raw, Gram[45] raw
    __shared__ float stats2[4][68];     // S1[54], S2[6], S3[6]
    __shared__ float noT[4][6][128];    // node_outer transposed

    const int   cntn = cnt[n];
    const int   cnE  = min(cntn, slot);
    const float invc = 1.f / (float)(cntn > 0 ? cntn : 1);
    const float inv128 = 1.f / 128.f;

    // ---- emb[n] two channels per lane, in registers ----
    const int c0 = lane, c1 = lane + 64;
    const float* eb = emb + (size_t)n * 1152;
    float er0[9], er1[9];
    #pragma unroll
    for (int l = 0; l < 9; ++l) { er0[l] = eb[l * 128 + c0]; er1[l] = eb[l * 128 + c1]; }

    const float spw0 = sph_w[0], spw1 = sph_w[1], spw2 = sph_w[2];

    // ---- stats partials + DPP reduce: mbar[9], Gram[45] ----
    {
        #pragma unroll
        for (int l = 0; l < 9; ++l) {
            const float tot = dpp_sum64(er0[l] + er1[l]);
            if (lane == 63) statsL[wv][l] = tot;
        }
        int idx = 9;
        #pragma unroll
        for (int l = 0; l < 9; ++l) {
            #pragma unroll
            for (int l2 = l; l2 < 9; ++l2) {
                const float tot = dpp_sum64(er0[l] * er0[l2] + er1[l] * er1[l2]);
                if (lane == 63) statsL[wv][idx] = tot;
                ++idx;
            }
        }
    }
    wave_fence();

    // ---- edge phase: lane e owns edge e (cnE <= 64 by construction) ----
    if (lane < cnE) {
        const int e = elist[(size_t)n * slot + lane];
        const float vx = vec[e * 3 + 0];
        const float vy = vec[e * 3 + 1];
        const float vz = vec[e * 3 + 2];
        const float rr = vx * vx + vy * vy + vz * vz;

        const float a1x = SQ3 * vx, a1y = SQ3 * vy, a1z = SQ3 * vz;
        const float q0 = SQ15 * vx * vy;
        const float q1 = SQ15 * vy * vz;
        const float q2 = 0.5f * SQ5 * (3.f * vz * vz - rr);
        const float q3 = SQ15 * vx * vz;
        const float q4 = 0.5f * SQ15 * (vx * vx - vy * vy);
        const float inv1 = spw1 * rsqrtf((a1x*a1x + a1y*a1y + a1z*a1z) * (1.f/3.f) + 1e-6f);
        const float inv2 = spw2 * rsqrtf((q0*q0 + q1*q1 + q2*q2 + q3*q3 + q4*q4) * (1.f/5.f) + 1e-6f);

        float sh[9];
        sh[0] = spw0 * rsqrtf(1.0f + 1e-6f);
        sh[1] = a1x * inv1; sh[2] = a1y * inv1; sh[3] = a1z * inv1;
        sh[4] = q0 * inv2;  sh[5] = q1 * inv2;  sh[6] = q2 * inv2;
        sh[7] = q3 * inv2;  sh[8] = q4 * inv2;

        float mu = 0.f;
        #pragma unroll
        for (int l = 0; l < 9; ++l) mu += sh[l] * statsL[wv][l];
        mu *= inv128;

        float x2 = 0.f;
        {
            int idx = 9;
            #pragma unroll
            for (int l = 0; l < 9; ++l) {
                #pragma unroll
                for (int l2 = l; l2 < 9; ++l2) {
                    const float coef = (l == l2) ? 1.f : 2.f;
                    x2 += statsL[wv][idx] * (coef * sh[l] * sh[l2]);
                    ++idx;
                }
            }
        }
        x2 *= inv128;

        const float var  = x2 - mu * mu;
        const float rinv = rsqrtf(var + 1e-5f);

        const float4 wA = {rinv*sh[0], rinv*sh[1], rinv*sh[2], rinv*sh[3]};
        const float4 wB = {rinv*sh[4], rinv*sh[5], rinv*sh[6], rinv*sh[7]};
        const float4 wC = {rinv*sh[8], rinv*mu, vx*vx, vx*vy};
        const float4 wD = {vx*vz, vy*vy, vy*vz, vz*vz};
        *(float4*)&escr[wv][lane][0]  = wA;
        *(float4*)&escr[wv][lane][4]  = wB;
        *(float4*)&escr[wv][lane][8]  = wC;
        *(float4*)&escr[wv][lane][12] = wD;
        escr[wv][lane][16] = 1.0f;
    }
    wave_fence();

    // ---- S reduce over edges: lane j owns component j ----
    // cols: 0..8 = t1[l], 9 = mru, 10..15 = op[0..5], 16 = 1.0
    {
        int a, b;
        const int j = lane;
        if (j < 54)      { a = j % 9;          b = 10 + j / 9; }
        else if (j < 60) { a = 9;              b = 10 + (j - 54); }
        else             { a = 10 + (j - 60);  b = 16; }
        const int a2 = 14 + (lane & 1);

        float s = 0.f, s2 = 0.f;
        for (int e = 0; e < cnE; ++e) {
            const float* row = &escr[wv][e][0];
            s  += row[a] * row[b];
            s2 += row[a2];
        }
        stats2[wv][lane] = s;
        if (lane < 2) stats2[wv][64 + lane] = s2;
    }
    wave_fence();

    // ---- contraction: no[u][c] = invc*(lw_c*(emb_lc.S1[u] - S2[u]) + lb_c*S3[u]) ----
    {
        const float lw0 = ln_w[c0], lb0 = ln_b[c0];
        const float lw1 = ln_w[c1], lb1 = ln_b[c1];
        #pragma unroll
        for (int u = 0; u < 6; ++u) {
            float a0 = 0.f, a1 = 0.f;
            #pragma unroll
            for (int l = 0; l < 9; ++l) {
                const float s1v = stats2[wv][9 * u + l];
                a0 += er0[l] * s1v;
                a1 += er1[l] * s1v;
            }
            const float S2u = stats2[wv][54 + u];
            const float S3u = stats2[wv][60 + u];
            noT[wv][u][c0] = (lw0 * (a0 - S2u) + lb0 * S3u) * invc;
            noT[wv][u][c1] = (lw1 * (a1 - S2u) + lb1 * S3u) * invc;
        }
    }
    wave_fence();

    // ---- MLP: lane owns k0=2*lane, k1=2*lane+1 ----
    float2 hh[6];
    #pragma unroll
    for (int u = 0; u < 6; ++u) { hh[u].x = 0.f; hh[u].y = 0.f; }
    {
        const float* w1base = W1 + 2 * lane;
        for (int c4 = 0; c4 < 32; ++c4) {
            float4 nv[6];
            #pragma unroll
            for (int u = 0; u < 6; ++u) nv[u] = *(const float4*)&noT[wv][u][c4 * 4];
            #pragma unroll
            for (int cc = 0; cc < 4; ++cc) {
                const float2 w = *(const float2*)(w1base + (size_t)(c4 * 4 + cc) * 128);
                #pragma unroll
                for (int u = 0; u < 6; ++u) {
                    const float s = ((const float*)&nv[u])[cc];
                    hh[u].x = fmaf(s, w.x, hh[u].x);
                    hh[u].y = fmaf(s, w.y, hh[u].y);
                }
            }
        }
    }

    // silu + W2 dot + DPP reduce + atomic scatter
    {
        const float2 b1v = *(const float2*)&b1[2 * lane];
        const float2 w2v = *(const float2*)&W2[2 * lane];
        float sv[6];
        #pragma unroll
        for (int u = 0; u < 6; ++u) {
            const float zx = hh[u].x + b1v.x;
            const float zy = hh[u].y + b1v.y;
            const float gx = zx / (1.f + __expf(-zx));
            const float gy = zy / (1.f + __expf(-zy));
            sv[u] = gx * w2v.x + gy * w2v.y;
        }
        float tot[6];
        #pragma unroll
        for (int u = 0; u < 6; ++u) tot[u] = dpp_sum64(sv[u]);
        if (lane == 63) {
            const float bb = b2[0];
            const int base = batch[n] * 9;
            atomicAdd(&r2s[base + 0], tot[0] + bb);
            atomicAdd(&r2s[base + 1], tot[1] + bb);
            atomicAdd(&r2s[base + 2], tot[2] + bb);
            atomicAdd(&r2s[base + 3], tot[1] + bb);
            atomicAdd(&r2s[base + 4], tot[3] + bb);
            atomicAdd(&r2s[base + 5], tot[4] + bb);
            atomicAdd(&r2s[base + 6], tot[2] + bb);
            atomicAdd(&r2s[base + 7], tot[4] + bb);
            atomicAdd(&r2s[base + 8], tot[5] + bb);
        }
    }
}

__global__ void finalize_kernel(const float* __restrict__ r2s, const int* __restrict__ bcnt,
                                float* __restrict__ out, int M) {
    int i = blockIdx.x * blockDim.x + threadIdx.x;
    if (i < M) {
        int b = i / 9;
        int cb = bcnt[b];
        out[i] = r2s[i] / (float)(cb > 0 ? cb : 1);
    }
}

extern "C" void kernel_launch(void* const* d_in, const int* in_sizes, int n_in,
                              void* d_out, int out_size, void* d_ws, size_t ws_size,
                              hipStream_t stream) {
    const float* emb   = (const float*)d_in[0];
    const float* vec   = (const float*)d_in[1];
    const int*   eidx  = (const int*)  d_in[2];
    const int*   batch = (const int*)  d_in[3];
    const float* sph_w = (const float*)d_in[4];
    const float* ln_w  = (const float*)d_in[5];
    const float* ln_b  = (const float*)d_in[6];
    const float* W1    = (const float*)d_in[7];
    const float* b1    = (const float*)d_in[8];
    const float* W2    = (const float*)d_in[9];
    const float* b2    = (const float*)d_in[10];

    const int N = in_sizes[3];
    const int E = in_sizes[1] / 3;
    const int B = out_size / 9;
    const int* idx1 = eidx + E;   // edge_index[1]

    // ws layout: [cnt N][bcnt B][r2s B*9][elist N*slot]
    int*   cnt   = (int*)d_ws;
    int*   bcnt  = cnt + N;
    float* r2s   = (float*)(bcnt + B);
    int*   elist = (int*)(r2s + B * 9);

    const size_t fixed = (size_t)(N + B + B * 9) * 4;
    int slot = 64;
    if (ws_size < fixed + (size_t)N * slot * 4) {
        size_t avail = (ws_size > fixed) ? (ws_size - fixed) / ((size_t)N * 4) : 1;
        slot = (int)avail;
        if (slot > 64) slot = 64;
        if (slot < 1)  slot = 1;
    }

    hipMemsetAsync(cnt, 0, fixed, stream);

    const int pthreads = 256;
    const int pwork = max((E + 3) / 4, N);
    preproc_kernel<<<(pwork + pthreads - 1) / pthreads, pthreads, 0, stream>>>(
        idx1, batch, cnt, bcnt, elist, slot, E, N);
    node_kernel<<<(N + 3) / 4, 256, 0, stream>>>(emb, vec, cnt, elist, slot,
                                                 sph_w, ln_w, ln_b, W1, b1, W2, b2,
                                                 batch, r2s, N);
    finalize_kernel<<<(B * 9 + 255) / 256, 256, 0, stream>>>(r2s, bcnt, (float*)d_out, B * 9);
}

// Round 5
// 154.543 us; speedup vs baseline: 1.2017x; 1.2017x over previous
//
#include <hip/hip_runtime.h>

// Rank2SymmetricTensorHead — split-phase, algebra-factored.
// layernorm is affine per edge => per-node S1[6][9],S2[6],S3[6] suffice;
// per-edge mu/var from per-node mbar[9] + Gram[45] of emb.
// K1 prep: edge bucketing (atomics) || node stats (DPP, no LDS)
// K2 edges: wave/node, lane/edge, 66 DPP-reduced sums -> S (pre-divided by cnt)
// K3 mlp: 4 nodes/block contraction + tiled MLP, atomicAdd(out/bcnt) directly.

#define SQ3  1.73205080756887729f
#define SQ15 3.87298334620741688f
#define SQ5  2.23606797749978970f

__device__ __forceinline__ float dpp_sum64(float v) {
    // 64-lane sum, result valid in lane 63. Pure VALU.
    int x;
    x = __builtin_amdgcn_update_dpp(0, __float_as_int(v), 0x111, 0xF, 0xF, true); v += __int_as_float(x);
    x = __builtin_amdgcn_update_dpp(0, __float_as_int(v), 0x112, 0xF, 0xF, true); v += __int_as_float(x);
    x = __builtin_amdgcn_update_dpp(0, __float_as_int(v), 0x114, 0xF, 0xF, true); v += __int_as_float(x);
    x = __builtin_amdgcn_update_dpp(0, __float_as_int(v), 0x118, 0xF, 0xF, true); v += __int_as_float(x);
    x = __builtin_amdgcn_update_dpp(0, __float_as_int(v), 0x142, 0xA, 0xF, true); v += __int_as_float(x);
    x = __builtin_amdgcn_update_dpp(0, __float_as_int(v), 0x143, 0xC, 0xF, true); v += __int_as_float(x);
    return v;
}

// blocks [0,PB): edge bucketing + per-batch node count
// blocks [PB,..): per-node stats, 1 wave per node, no LDS
__global__ __launch_bounds__(256)
void prep_kernel(const int* __restrict__ idx1, const int* __restrict__ batch,
                 int* __restrict__ cnt, int* __restrict__ bcnt, int* __restrict__ elist,
                 const float* __restrict__ emb, float* __restrict__ stats,
                 int slot, int E, int N, int PB)
{
    if ((int)blockIdx.x < PB) {
        const int i  = blockIdx.x * 256 + threadIdx.x;
        const int i4 = i * 4;
        if (i4 + 3 < E) {
            const int4 v = *(const int4*)&idx1[i4];
            int p;
            p = atomicAdd(&cnt[v.x], 1); if (p < slot) elist[(size_t)v.x * slot + p] = i4;
            p = atomicAdd(&cnt[v.y], 1); if (p < slot) elist[(size_t)v.y * slot + p] = i4 + 1;
            p = atomicAdd(&cnt[v.z], 1); if (p < slot) elist[(size_t)v.z * slot + p] = i4 + 2;
            p = atomicAdd(&cnt[v.w], 1); if (p < slot) elist[(size_t)v.w * slot + p] = i4 + 3;
        } else {
            for (int k2 = i4; k2 < E; ++k2) {
                const int nn = idx1[k2];
                const int p = atomicAdd(&cnt[nn], 1);
                if (p < slot) elist[(size_t)nn * slot + p] = k2;
            }
        }
        if (i < N) atomicAdd(&bcnt[batch[i]], 1);
        return;
    }
    const int lane = threadIdx.x & 63;
    const int n = ((int)blockIdx.x - PB) * 4 + (threadIdx.x >> 6);
    if (n >= N) return;

    const float* eb = emb + (size_t)n * 1152;
    float er0[9], er1[9];
    #pragma unroll
    for (int l = 0; l < 9; ++l) { er0[l] = eb[l * 128 + lane]; er1[l] = eb[l * 128 + 64 + lane]; }

    float* st = stats + (size_t)n * 56;
    #pragma unroll
    for (int l = 0; l < 9; ++l) {
        const float tot = dpp_sum64(er0[l] + er1[l]);
        if (lane == 63) st[l] = tot;
    }
    int idx = 9;
    #pragma unroll
    for (int l = 0; l < 9; ++l) {
        #pragma unroll
        for (int l2 = l; l2 < 9; ++l2) {
            const float tot = dpp_sum64(er0[l] * er0[l2] + er1[l] * er1[l2]);
            if (lane == 63) st[idx] = tot;
            ++idx;
        }
    }
}

// wave per node, lane per edge; S[n][68] = {S1[54],S2[6],S3[6]} * (1/cnt)
__global__ __launch_bounds__(256)
void edges_kernel(const float* __restrict__ vec, const int* __restrict__ cnt,
                  const int* __restrict__ elist, int slot,
                  const float* __restrict__ sph_w, const float* __restrict__ stats,
                  float* __restrict__ S, int N)
{
    const int lane = threadIdx.x & 63;
    const int n = blockIdx.x * 4 + (threadIdx.x >> 6);
    if (n >= N) return;

    const int   cntn = cnt[n];
    const int   cnE  = min(cntn, slot);
    const float invc = 1.f / (float)(cntn > 0 ? cntn : 1);
    const float inv128 = 1.f / 128.f;
    const float* st = stats + (size_t)n * 56;   // wave-uniform -> scalar loads

    float t1[9], mru, op[6];
    #pragma unroll
    for (int l = 0; l < 9; ++l) t1[l] = 0.f;
    mru = 0.f;
    #pragma unroll
    for (int u = 0; u < 6; ++u) op[u] = 0.f;

    if (lane < cnE) {
        const int e = elist[(size_t)n * slot + lane];
        const float vx = vec[e * 3 + 0];
        const float vy = vec[e * 3 + 1];
        const float vz = vec[e * 3 + 2];
        const float rr = vx * vx + vy * vy + vz * vz;

        const float a1x = SQ3 * vx, a1y = SQ3 * vy, a1z = SQ3 * vz;
        const float q0 = SQ15 * vx * vy;
        const float q1 = SQ15 * vy * vz;
        const float q2 = 0.5f * SQ5 * (3.f * vz * vz - rr);
        const float q3 = SQ15 * vx * vz;
        const float q4 = 0.5f * SQ15 * (vx * vx - vy * vy);
        const float inv1 = sph_w[1] * rsqrtf((a1x*a1x + a1y*a1y + a1z*a1z) * (1.f/3.f) + 1e-6f);
        const float inv2 = sph_w[2] * rsqrtf((q0*q0 + q1*q1 + q2*q2 + q3*q3 + q4*q4) * (1.f/5.f) + 1e-6f);

        float sh[9];
        sh[0] = sph_w[0] * rsqrtf(1.0f + 1e-6f);
        sh[1] = a1x * inv1; sh[2] = a1y * inv1; sh[3] = a1z * inv1;
        sh[4] = q0 * inv2;  sh[5] = q1 * inv2;  sh[6] = q2 * inv2;
        sh[7] = q3 * inv2;  sh[8] = q4 * inv2;

        float mu = 0.f;
        #pragma unroll
        for (int l = 0; l < 9; ++l) mu += sh[l] * st[l];
        mu *= inv128;

        float x2 = 0.f;
        {
            int idx = 9;
            #pragma unroll
            for (int l = 0; l < 9; ++l) {
                x2 += st[idx] * sh[l] * sh[l]; ++idx;
                #pragma unroll
                for (int l2 = l + 1; l2 < 9; ++l2) {
                    x2 += st[idx] * (2.f * sh[l] * sh[l2]); ++idx;
                }
            }
        }
        x2 *= inv128;

        const float rinv = rsqrtf(x2 - mu * mu + 1e-5f);
        #pragma unroll
        for (int l = 0; l < 9; ++l) t1[l] = rinv * sh[l];
        mru = rinv * mu;
        op[0] = vx*vx; op[1] = vx*vy; op[2] = vx*vz;
        op[3] = vy*vy; op[4] = vy*vz; op[5] = vz*vz;
    }

    float* Sp = S + (size_t)n * 68;
    #pragma unroll
    for (int u = 0; u < 6; ++u) {
        #pragma unroll
        for (int l = 0; l < 9; ++l) {
            const float tot = dpp_sum64(op[u] * t1[l]);
            if (lane == 63) Sp[u * 9 + l] = tot * invc;
        }
    }
    #pragma unroll
    for (int u = 0; u < 6; ++u) {
        const float tot = dpp_sum64(op[u] * mru);
        if (lane == 63) Sp[54 + u] = tot * invc;
    }
    #pragma unroll
    for (int u = 0; u < 6; ++u) {
        const float tot = dpp_sum64(op[u]);
        if (lane == 63) Sp[60 + u] = tot * invc;
    }
}

// 4 nodes per block: contraction -> no_lds[24][128], then MLP (rows-split),
// silu, W2 dot, DPP+LDS reduce, atomicAdd(out + b*9+j, val/bcnt).
__global__ __launch_bounds__(256)
void mlp_kernel(const float* __restrict__ emb, const float* __restrict__ S,
                const float* __restrict__ ln_w, const float* __restrict__ ln_b,
                const float* __restrict__ W1, const float* __restrict__ b1,
                const float* __restrict__ W2, const float* __restrict__ b2,
                const int* __restrict__ batch, const int* __restrict__ bcnt,
                float* __restrict__ out, int N)
{
    __shared__ float no_lds[24][128];   // row = nid*6+u
    __shared__ float red[4][12];

    const int t  = threadIdx.x;
    const int nb = blockIdx.x * 4;
    const int k  = t & 127, uh = t >> 7;

    // ---- phase A: contraction ----
    const float lw = ln_w[k], lb = ln_b[k];
    #pragma unroll
    for (int nid = 0; nid < 4; ++nid) {
        const int n = nb + nid;
        const int nc = (n < N) ? n : (N - 1);
        const float* eb = emb + (size_t)nc * 1152;
        float e[9];
        #pragma unroll
        for (int l = 0; l < 9; ++l) e[l] = eb[l * 128 + k];
        const float* Sp = S + (size_t)nc * 68;   // wave-uniform -> scalar loads
        #pragma unroll
        for (int du = 0; du < 3; ++du) {
            const int u = uh * 3 + du;
            float a = 0.f;
            #pragma unroll
            for (int l = 0; l < 9; ++l) a += e[l] * Sp[u * 9 + l];
            no_lds[nid * 6 + u][k] = lw * (a - Sp[54 + u]) + lb * Sp[60 + u];
        }
    }
    __syncthreads();

    // ---- phase B: GEMM, thread = (kp, row-half), full c-range ----
    const int kp = k, rh = uh;            // rows rh*12 .. rh*12+11
    float acc[12];
    #pragma unroll
    for (int r = 0; r < 12; ++r) acc[r] = 0.f;
    for (int c4 = 0; c4 < 32; ++c4) {
        float4 nr[12];
        #pragma unroll
        for (int r = 0; r < 12; ++r) nr[r] = *(const float4*)&no_lds[rh * 12 + r][c4 * 4];
        #pragma unroll
        for (int cc = 0; cc < 4; ++cc) {
            const float w = W1[(size_t)(c4 * 4 + cc) * 128 + kp];
            #pragma unroll
            for (int r = 0; r < 12; ++r)
                acc[r] = fmaf(((const float*)&nr[r])[cc], w, acc[r]);
        }
    }

    // ---- phase C: silu + W2 + reduce ----
    const float b1k = b1[kp], w2k = W2[kp];
    float sv[12];
    #pragma unroll
    for (int r = 0; r < 12; ++r) {
        const float z = acc[r] + b1k;
        const float s = z / (1.f + __expf(-z));
        sv[r] = s * w2k;
    }
    #pragma unroll
    for (int r = 0; r < 12; ++r) sv[r] = dpp_sum64(sv[r]);
    const int wid = t >> 6;
    if ((t & 63) == 63) {
        #pragma unroll
        for (int r = 0; r < 12; ++r) red[wid][r] = sv[r];
    }
    __syncthreads();

    if (t < 36) {
        const int nid = t / 9, j = t - nid * 9;
        const int n = nb + nid;
        if (n < N) {
            const int umap[9] = {0, 1, 2, 1, 3, 4, 2, 4, 5};
            const int g  = nid * 6 + umap[j];
            const int rh2 = g / 12, rr = g - rh2 * 12;
            const float val = red[rh2 * 2 + 0][rr] + red[rh2 * 2 + 1][rr] + b2[0];
            const int bb = batch[n];
            const int cb = bcnt[bb];
            const float ic = 1.f / (float)(cb > 0 ? cb : 1);
            atomicAdd(&out[bb * 9 + j], val * ic);
        }
    }
}

extern "C" void kernel_launch(void* const* d_in, const int* in_sizes, int n_in,
                              void* d_out, int out_size, void* d_ws, size_t ws_size,
                              hipStream_t stream) {
    const float* emb   = (const float*)d_in[0];
    const float* vec   = (const float*)d_in[1];
    const int*   eidx  = (const int*)  d_in[2];
    const int*   batch = (const int*)  d_in[3];
    const float* sph_w = (const float*)d_in[4];
    const float* ln_w  = (const float*)d_in[5];
    const float* ln_b  = (const float*)d_in[6];
    const float* W1    = (const float*)d_in[7];
    const float* b1    = (const float*)d_in[8];
    const float* W2    = (const float*)d_in[9];
    const float* b2    = (const float*)d_in[10];

    const int N = in_sizes[3];
    const int E = in_sizes[1] / 3;
    const int B = out_size / 9;
    const int* idx1 = eidx + E;   // edge_index[1]

    // ws: [cnt N][bcnt B][elist N*slot][stats N*56][S N*68]
    int slot = 64;
    {
        const size_t base = (size_t)(N + B) + (size_t)N * (56 + 68);
        while (slot > 1 && (base + (size_t)N * slot) * 4 > ws_size) slot >>= 1;
    }
    int*   cnt   = (int*)d_ws;
    int*   bcnt  = cnt + N;
    int*   elist = bcnt + B;
    float* stats = (float*)(elist + (size_t)N * slot);
    float* S     = stats + (size_t)N * 56;

    hipMemsetAsync(d_out, 0, (size_t)out_size * sizeof(float), stream);
    hipMemsetAsync(cnt, 0, (size_t)(N + B) * sizeof(int), stream);

    const int PB = (max((E + 3) / 4, N) + 255) / 256;
    const int SB = (N + 3) / 4;
    prep_kernel<<<PB + SB, 256, 0, stream>>>(idx1, batch, cnt, bcnt, elist,
                                             emb, stats, slot, E, N, PB);
    edges_kernel<<<(N + 3) / 4, 256, 0, stream>>>(vec, cnt, elist, slot,
                                                  sph_w, stats, S, N);
    mlp_kernel<<<(N + 3) / 4, 256, 0, stream>>>(emb, S, ln_w, ln_b,
                                                W1, b1, W2, b2,
                                                batch, bcnt, (float*)d_out, N);
}